// Round 17
// baseline (81.717 us; speedup 1.0000x reference)
//
#include <hip/hip_runtime.h>
#include <hip/hip_bf16.h>

// MILAttentionPool: B=32, L=2048, D=512, H=256, K=4
// out[b, k*512+d] = sum_l softmax_l(logit[b,l,k]) * x[b*L+l, d]
// logit = (tanh(x@W1+b1)*sigmoid(x@W3+b3)) @ W2   (+b2 cancels in softmax)
//
// R17 = R14 (best: 78.7us) with the part round-trip removed:
//  - pool partials accumulate via fp32 atomicAdd into a 256KB output-shaped
//    buffer (32 contenders/address, L2-absorbed) instead of 4MB bf16 part
//  - psum likewise atomically accumulated per bag
//  - k_div: out = outacc / psum  (0.5MB traffic vs 4.25MB)
//  - outacc+psacc zeroed per call via hipMemsetAsync (graph-capturable)
// R14 architecture rationale: 64-row tile, 512thr/8 waves, wave 64x64(concat),
// B per-lane from L2 (wc 512KB L2-resident), chunk-major LDS (0 conflicts),
// manual-RNE cvt, rcp-form gate. 4 waves/SIMD is the joint LDS+reg optimum
// (R15 smaller tiles and R10-13 prefetch variants all measured worse).

typedef short  bf16x8 __attribute__((ext_vector_type(8)));
typedef float  f32x4  __attribute__((ext_vector_type(4)));

#define D_IN    512
#define H_DIM   256
#define L_BAG   2048

// manual round-to-nearest-even fp32->bf16 (finite inputs only)
__device__ __forceinline__ short f2bf(float f) {
  union { float f; unsigned u; } u;
  u.f = f;
  unsigned r = u.u + 0x7FFFu + ((u.u >> 16) & 1u);
  return (short)(r >> 16);
}
__device__ __forceinline__ float bf2f(short s) {
  union { float f; unsigned u; } u;
  u.u = ((unsigned)(unsigned short)s) << 16;
  return u.f;
}

// ---------------- k0: concat-interleaved, chunk-major bf16 weights ----------------
// wc short idx = kt*16384 + (c*512 + n_c)*8 + r   (k = kt*32 + c*8 + r)
//   n_c: g=n_c>>5, j=n_c&31; j<16 -> W1[:, g*16+j] else W3[:, g*16+j-16]
__global__ __launch_bounds__(256) void k_prep_w(const float* __restrict__ W1,
                                                const float* __restrict__ W3,
                                                short* __restrict__ wc) {
  int t = blockIdx.x * 256 + threadIdx.x;   // 0..32767
  int n_c = t & 511;
  int kc  = t >> 9;            // k-chunk of 8: 0..63
  int kt = kc >> 2, c = kc & 3;
  int g = n_c >> 5, j = n_c & 31;
  const float* src = (j < 16) ? W1 : W3;
  int h = g * 16 + (j & 15);
  bf16x8 v;
  #pragma unroll
  for (int r = 0; r < 8; ++r) v[r] = f2bf(src[(kc * 8 + r) * H_DIM + h]);
  *(bf16x8*)(wc + kt * 16384 + (c * 512 + n_c) * 8) = v;
}

// ---------------- k1: fused stage + GEMM + gate@W2 + exp + pool ----------------
// 512 thr = 8 waves; wave w owns concat cols [w*64, w*64+64) (= H cols [w*32,+32)).
__global__ __launch_bounds__(512, 4) void k_fused(
    const float* __restrict__ x,
    const short* __restrict__ wc,
    const float* __restrict__ b1, const float* __restrict__ b3,
    const float* __restrict__ W2,
    float* __restrict__ outacc, float* __restrict__ psacc)
{
  __shared__ __align__(16) short xbf[64 * 512];     // 64 KB, chunk-major [kc][row][8]
  __shared__ float lpart[8][64][4];                 //  8 KB
  __shared__ __align__(16) float wlds[64 * 4];      //  1 KB
  __shared__ float psc[4][4];                       // (total ~73 KB -> 2 blocks/CU)

  const int tid  = threadIdx.x;
  const int lane = tid & 63;
  const int w    = tid >> 6;
  const int l15  = lane & 15;
  const int q    = lane >> 4;
  const int blk  = blockIdx.x;
  const long row0 = (long)blk * 64;

  // ---- stage x tile: 64 rows x 512 k, fp32 -> bf16, chunk-major ----
  {
    const int r   = tid & 63;
    const int kc0 = (tid >> 6) * 8;
    const float* xr = x + (row0 + r) * D_IN + kc0 * 8;
    #pragma unroll
    for (int j = 0; j < 8; ++j) {
      float4 f0 = ((const float4*)(xr + j * 8))[0];
      float4 f1 = ((const float4*)(xr + j * 8))[1];
      bf16x8 v;
      v[0] = f2bf(f0.x); v[1] = f2bf(f0.y); v[2] = f2bf(f0.z); v[3] = f2bf(f0.w);
      v[4] = f2bf(f1.x); v[5] = f2bf(f1.y); v[6] = f2bf(f1.z); v[7] = f2bf(f1.w);
      *(bf16x8*)&xbf[((kc0 + j) * 64 + r) * 8] = v;   // consecutive lanes contiguous
    }
  }
  __syncthreads();

  // ---- GEMM: acc[mf 4][nf 4]; B per-lane from L2 (plain loop, R8-style) ----
  f32x4 acc[4][4];
  #pragma unroll
  for (int mf = 0; mf < 4; ++mf)
    #pragma unroll
    for (int nf = 0; nf < 4; ++nf) acc[mf][nf] = (f32x4){0.f, 0.f, 0.f, 0.f};

  const short* bgp = wc + (q * 512 + w * 64 + l15) * 8;

  #pragma unroll 1
  for (int kt = 0; kt < 16; ++kt) {
    bf16x8 af[4], bfr[4];
    const short* bk = bgp + kt * 16384;
    #pragma unroll
    for (int nf = 0; nf < 4; ++nf)
      bfr[nf] = *(const bf16x8*)(bk + nf * 128);
    const int ab = (kt * 4 + q) * 512 + l15 * 8;
    #pragma unroll
    for (int mf = 0; mf < 4; ++mf)
      af[mf] = *(const bf16x8*)&xbf[ab + mf * 128];
    #pragma unroll
    for (int mf = 0; mf < 4; ++mf)
      #pragma unroll
      for (int nf = 0; nf < 4; ++nf)
        acc[mf][nf] = __builtin_amdgcn_mfma_f32_16x16x32_bf16(af[mf], bfr[nf], acc[mf][nf], 0, 0, 0);
  }

  // ---- epilogue: gate + @W2, per-mf to limit register pressure ----
  float b1v[2], b3v[2];
  f32x4 wv[2];
  #pragma unroll
  for (int p = 0; p < 2; ++p) {
    int h = w * 32 + p * 16 + l15;
    b1v[p] = b1[h];
    b3v[p] = b3[h];
    wv[p] = *(const f32x4*)&W2[h * 4];
  }
  #pragma unroll
  for (int mf = 0; mf < 4; ++mf) {
    float pl[4][4];
    #pragma unroll
    for (int j = 0; j < 4; ++j)
      #pragma unroll
      for (int kk = 0; kk < 4; ++kk) pl[j][kk] = 0.f;
    #pragma unroll
    for (int p = 0; p < 2; ++p)
      #pragma unroll
      for (int j = 0; j < 4; ++j) {
        float h1 = acc[mf][2 * p][j]     + b1v[p];
        float h3 = acc[mf][2 * p + 1][j] + b3v[p];
        // g = tanh(h1)*sigmoid(h3) = (A-1) / ((A+1)*(1+B)), A=e^{2h1}, B=e^{-h3}
        float A = __expf(2.f * h1);
        float B = __expf(-h3);
        float g = (A - 1.f) * __builtin_amdgcn_rcpf((A + 1.f) * (1.f + B));
        pl[j][0] += g * wv[p][0];
        pl[j][1] += g * wv[p][1];
        pl[j][2] += g * wv[p][2];
        pl[j][3] += g * wv[p][3];
      }
    #pragma unroll
    for (int off = 1; off < 16; off <<= 1)
      #pragma unroll
      for (int j = 0; j < 4; ++j)
        #pragma unroll
        for (int kk = 0; kk < 4; ++kk)
          pl[j][kk] += __shfl_xor(pl[j][kk], off);
    if (l15 == 0) {
      #pragma unroll
      for (int j = 0; j < 4; ++j)
        #pragma unroll
        for (int kk = 0; kk < 4; ++kk)
          lpart[w][mf * 16 + q * 4 + j][kk] = pl[j][kk];
    }
  }
  __syncthreads();

  // ---- logits sum across waves, exp (no max: logits ~N(0,0.3)), psum atomic ----
  if (tid < 256) {
    const int r = tid >> 2, kk = tid & 3;
    float lg = 0.f;
    #pragma unroll
    for (int ww = 0; ww < 8; ++ww) lg += lpart[ww][r][kk];
    float e = __expf(lg);
    wlds[r * 4 + kk] = e;
    float v = e;
    #pragma unroll
    for (int o = 4; o < 64; o <<= 1) v += __shfl_xor(v, o);
    if (lane < 4) psc[tid >> 6][lane] = v;   // lane == kk for lanes 0..3
  }
  __syncthreads();
  if (tid < 4)
    atomicAdd(&psacc[(blk >> 5) * 4 + tid],
              psc[0][tid] + psc[1][tid] + psc[2][tid] + psc[3][tid]);

  // ---- pooling from LDS, kc-rotated row order; fp32 atomic accumulate ----
  {
    const int d  = tid;            // 0..511
    const int kc = d >> 3;
    const int e  = d & 7;
    const short* xcol = &xbf[kc * 512 + e];
    float a0 = 0.f, a1 = 0.f, a2 = 0.f, a3 = 0.f;
    #pragma unroll 8
    for (int ii = 0; ii < 64; ++ii) {
      int l = (ii + kc) & 63;                       // rotation: wave hits all 32 banks
      float xf = bf2f(xcol[l * 8]);
      float4 wv4 = *(const float4*)&wlds[l * 4];
      a0 += wv4.x * xf; a1 += wv4.y * xf; a2 += wv4.z * xf; a3 += wv4.w * xf;
    }
    float* oa = outacc + (long)(blk >> 5) * 2048 + d;   // bag = blk/32
    atomicAdd(oa,        a0);
    atomicAdd(oa +  512, a1);
    atomicAdd(oa + 1024, a2);
    atomicAdd(oa + 1536, a3);
  }
}

// ---------------- k2: divide by per-bag softmax sum ----------------
__global__ __launch_bounds__(256) void k_div(const float* __restrict__ outacc,
                                             const float* __restrict__ psacc,
                                             float* __restrict__ out) {
  int idx = blockIdx.x * 256 + threadIdx.x;   // b*2048 + k*512 + d
  int b = idx >> 11, k = (idx >> 9) & 3;
  out[idx] = outacc[idx] / psacc[b * 4 + k];
}

extern "C" void kernel_launch(void* const* d_in, const int* in_sizes, int n_in,
                              void* d_out, int out_size, void* d_ws, size_t ws_size,
                              hipStream_t stream) {
  const float* x  = (const float*)d_in[0];
  const float* W1 = (const float*)d_in[1];
  const float* b1 = (const float*)d_in[2];
  const float* W3 = (const float*)d_in[3];
  const float* b3 = (const float*)d_in[4];
  const float* W2 = (const float*)d_in[5];
  // d_in[6] = b2: cancels in softmax; d_in[7] = bag_lengths: shapes only
  float* out = (float*)d_out;

  char* ws = (char*)d_ws;                    // ~0.78 MB used
  short* wc     = (short*)(ws + 0);          // 512 KB concat bf16 weights
  float* outacc = (float*)(ws + 524288);     // 256 KB [32][4][512] fp32 accum
  float* psacc  = (float*)(ws + 786432);     // 512 B  [32][4] softmax sums

  hipMemsetAsync(ws + 524288, 0, 262144 + 512, stream);   // zero outacc + psacc
  hipLaunchKernelGGL(k_prep_w, dim3(128),  dim3(256), 0, stream, W1, W3, wc);
  hipLaunchKernelGGL(k_fused,  dim3(1024), dim3(512), 0, stream, x, wc, b1, b3, W2, outacc, psacc);
  hipLaunchKernelGGL(k_div,    dim3(256),  dim3(256), 0, stream, outacc, psacc, out);
}

// Round 18
// 78.773 us; speedup vs baseline: 1.0374x; 1.0374x over previous
//
#include <hip/hip_runtime.h>
#include <hip/hip_bf16.h>

// MILAttentionPool: B=32, L=2048, D=512, H=256, K=4
// out[b, k*512+d] = sum_l softmax_l(logit[b,l,k]) * x[b*L+l, d]
// logit = (tanh(x@W1+b1)*sigmoid(x@W3+b3)) @ W2   (+b2 cancels in softmax)
//
// R18 = exact R14 revert (measured best: 78.7us). Final architecture:
//  - single pass over x (134MB = the dominant traffic), fused kernel per
//    64-row tile: stage x->LDS bf16 chunk-major (0 bank conflicts both for
//    GEMM frag reads and kc-rotated pooling reads)
//  - concat GEMM x@[W1|W3] (16-col interleave -> h1/h3 lane-local), bf16
//    MFMA 16x16x32, 8 waves x (64 rows x 64 concat cols), B per-lane from
//    L2-resident rearranged weights (512KB)
//  - fused gate (rcp form) + @W2 + exp (no max subtract: logits ~N(0,0.3))
//    + pooling of own rows from LDS; bf16 partials + per-tile softmax sums
//  - k_finalize: reduce 32 chunks/bag, divide by sum(exp)
// Measured-out alternatives: prefetch depth (scratch via rule #20), persistent
// blocks, gllds, raw barriers, smaller/larger tiles, atomics — all worse.

typedef short  bf16x8 __attribute__((ext_vector_type(8)));
typedef float  f32x4  __attribute__((ext_vector_type(4)));

#define D_IN    512
#define H_DIM   256
#define L_BAG   2048

// manual round-to-nearest-even fp32->bf16 (finite inputs only)
__device__ __forceinline__ short f2bf(float f) {
  union { float f; unsigned u; } u;
  u.f = f;
  unsigned r = u.u + 0x7FFFu + ((u.u >> 16) & 1u);
  return (short)(r >> 16);
}
__device__ __forceinline__ float bf2f(short s) {
  union { float f; unsigned u; } u;
  u.u = ((unsigned)(unsigned short)s) << 16;
  return u.f;
}

// ---------------- k0: concat-interleaved, chunk-major bf16 weights ----------------
// wc short idx = kt*16384 + (c*512 + n_c)*8 + r   (k = kt*32 + c*8 + r)
//   n_c: g=n_c>>5, j=n_c&31; j<16 -> W1[:, g*16+j] else W3[:, g*16+j-16]
__global__ __launch_bounds__(256) void k_prep_w(const float* __restrict__ W1,
                                                const float* __restrict__ W3,
                                                short* __restrict__ wc) {
  int t = blockIdx.x * 256 + threadIdx.x;   // 0..32767
  int n_c = t & 511;
  int kc  = t >> 9;            // k-chunk of 8: 0..63
  int kt = kc >> 2, c = kc & 3;
  int g = n_c >> 5, j = n_c & 31;
  const float* src = (j < 16) ? W1 : W3;
  int h = g * 16 + (j & 15);
  bf16x8 v;
  #pragma unroll
  for (int r = 0; r < 8; ++r) v[r] = f2bf(src[(kc * 8 + r) * H_DIM + h]);
  *(bf16x8*)(wc + kt * 16384 + (c * 512 + n_c) * 8) = v;
}

// ---------------- k1: fused stage + GEMM + gate@W2 + exp + pool ----------------
// 512 thr = 8 waves; wave w owns concat cols [w*64, w*64+64) (= H cols [w*32,+32)).
__global__ __launch_bounds__(512, 4) void k_fused(
    const float* __restrict__ x,
    const short* __restrict__ wc,
    const float* __restrict__ b1, const float* __restrict__ b3,
    const float* __restrict__ W2,
    short* __restrict__ part, float* __restrict__ psumP)
{
  __shared__ __align__(16) short xbf[64 * 512];     // 64 KB, chunk-major [kc][row][8]
  __shared__ float lpart[8][64][4];                 //  8 KB
  __shared__ __align__(16) float wlds[64 * 4];      //  1 KB
  __shared__ float psc[4][4];                       // (total ~73 KB -> 2 blocks/CU)

  const int tid  = threadIdx.x;
  const int lane = tid & 63;
  const int w    = tid >> 6;
  const int l15  = lane & 15;
  const int q    = lane >> 4;
  const int blk  = blockIdx.x;
  const long row0 = (long)blk * 64;

  // ---- stage x tile: 64 rows x 512 k, fp32 -> bf16, chunk-major ----
  {
    const int r   = tid & 63;
    const int kc0 = (tid >> 6) * 8;
    const float* xr = x + (row0 + r) * D_IN + kc0 * 8;
    #pragma unroll
    for (int j = 0; j < 8; ++j) {
      float4 f0 = ((const float4*)(xr + j * 8))[0];
      float4 f1 = ((const float4*)(xr + j * 8))[1];
      bf16x8 v;
      v[0] = f2bf(f0.x); v[1] = f2bf(f0.y); v[2] = f2bf(f0.z); v[3] = f2bf(f0.w);
      v[4] = f2bf(f1.x); v[5] = f2bf(f1.y); v[6] = f2bf(f1.z); v[7] = f2bf(f1.w);
      *(bf16x8*)&xbf[((kc0 + j) * 64 + r) * 8] = v;   // consecutive lanes contiguous
    }
  }
  __syncthreads();

  // ---- GEMM: acc[mf 4][nf 4]; B per-lane from L2 (plain loop, R8-style) ----
  f32x4 acc[4][4];
  #pragma unroll
  for (int mf = 0; mf < 4; ++mf)
    #pragma unroll
    for (int nf = 0; nf < 4; ++nf) acc[mf][nf] = (f32x4){0.f, 0.f, 0.f, 0.f};

  const short* bgp = wc + (q * 512 + w * 64 + l15) * 8;

  #pragma unroll 1
  for (int kt = 0; kt < 16; ++kt) {
    bf16x8 af[4], bfr[4];
    const short* bk = bgp + kt * 16384;
    #pragma unroll
    for (int nf = 0; nf < 4; ++nf)
      bfr[nf] = *(const bf16x8*)(bk + nf * 128);
    const int ab = (kt * 4 + q) * 512 + l15 * 8;
    #pragma unroll
    for (int mf = 0; mf < 4; ++mf)
      af[mf] = *(const bf16x8*)&xbf[ab + mf * 128];
    #pragma unroll
    for (int mf = 0; mf < 4; ++mf)
      #pragma unroll
      for (int nf = 0; nf < 4; ++nf)
        acc[mf][nf] = __builtin_amdgcn_mfma_f32_16x16x32_bf16(af[mf], bfr[nf], acc[mf][nf], 0, 0, 0);
  }

  // ---- epilogue: gate + @W2, per-mf to limit register pressure ----
  float b1v[2], b3v[2];
  f32x4 wv[2];
  #pragma unroll
  for (int p = 0; p < 2; ++p) {
    int h = w * 32 + p * 16 + l15;
    b1v[p] = b1[h];
    b3v[p] = b3[h];
    wv[p] = *(const f32x4*)&W2[h * 4];
  }
  #pragma unroll
  for (int mf = 0; mf < 4; ++mf) {
    float pl[4][4];
    #pragma unroll
    for (int j = 0; j < 4; ++j)
      #pragma unroll
      for (int kk = 0; kk < 4; ++kk) pl[j][kk] = 0.f;
    #pragma unroll
    for (int p = 0; p < 2; ++p)
      #pragma unroll
      for (int j = 0; j < 4; ++j) {
        float h1 = acc[mf][2 * p][j]     + b1v[p];
        float h3 = acc[mf][2 * p + 1][j] + b3v[p];
        // g = tanh(h1)*sigmoid(h3) = (A-1) / ((A+1)*(1+B)), A=e^{2h1}, B=e^{-h3}
        float A = __expf(2.f * h1);
        float B = __expf(-h3);
        float g = (A - 1.f) * __builtin_amdgcn_rcpf((A + 1.f) * (1.f + B));
        pl[j][0] += g * wv[p][0];
        pl[j][1] += g * wv[p][1];
        pl[j][2] += g * wv[p][2];
        pl[j][3] += g * wv[p][3];
      }
    #pragma unroll
    for (int off = 1; off < 16; off <<= 1)
      #pragma unroll
      for (int j = 0; j < 4; ++j)
        #pragma unroll
        for (int kk = 0; kk < 4; ++kk)
          pl[j][kk] += __shfl_xor(pl[j][kk], off);
    if (l15 == 0) {
      #pragma unroll
      for (int j = 0; j < 4; ++j)
        #pragma unroll
        for (int kk = 0; kk < 4; ++kk)
          lpart[w][mf * 16 + q * 4 + j][kk] = pl[j][kk];
    }
  }
  __syncthreads();

  // ---- logits sum across waves, exp (no max: logits ~N(0,0.3)), per-block psum ----
  if (tid < 256) {
    const int r = tid >> 2, kk = tid & 3;
    float lg = 0.f;
    #pragma unroll
    for (int ww = 0; ww < 8; ++ww) lg += lpart[ww][r][kk];
    float e = __expf(lg);
    wlds[r * 4 + kk] = e;
    float v = e;
    #pragma unroll
    for (int o = 4; o < 64; o <<= 1) v += __shfl_xor(v, o);
    if (lane < 4) psc[tid >> 6][lane] = v;   // lane == kk for lanes 0..3
  }
  __syncthreads();
  if (tid < 4) psumP[blk * 4 + tid] = psc[0][tid] + psc[1][tid] + psc[2][tid] + psc[3][tid];

  // ---- pooling from LDS, kc-rotated row order (conflict-free, no pad) ----
  {
    const int d  = tid;            // 0..511
    const int kc = d >> 3;
    const int e  = d & 7;
    const short* xcol = &xbf[kc * 512 + e];
    float a0 = 0.f, a1 = 0.f, a2 = 0.f, a3 = 0.f;
    #pragma unroll 8
    for (int ii = 0; ii < 64; ++ii) {
      int l = (ii + kc) & 63;                       // rotation: wave hits all 32 banks
      float xf = bf2f(xcol[l * 8]);
      float4 wv4 = *(const float4*)&wlds[l * 4];
      a0 += wv4.x * xf; a1 += wv4.y * xf; a2 += wv4.z * xf; a3 += wv4.w * xf;
    }
    short* pp = part + (long)blk * 2048 + d;
    pp[0]    = f2bf(a0);
    pp[512]  = f2bf(a1);
    pp[1024] = f2bf(a2);
    pp[1536] = f2bf(a3);
  }
}

// ---------------- k2: reduce 32 chunks per bag, divide by sum(exp) ----------------
__global__ __launch_bounds__(256) void k_finalize(const short* __restrict__ part,
                                                  const float* __restrict__ psumP,
                                                  float* __restrict__ out) {
  int idx = blockIdx.x * 256 + threadIdx.x;   // b*2048 + k*512 + d
  int b = idx >> 11, k = (idx >> 9) & 3, d = idx & 511;
  const short* pb = part + ((long)b * 32) * 2048 + k * 512 + d;
  float s = 0.f, ps = 0.f;
  #pragma unroll
  for (int c = 0; c < 32; ++c) {
    s  += bf2f(pb[c * 2048]);
    ps += psumP[(b * 32 + c) * 4 + k];
  }
  out[idx] = s / ps;
}

extern "C" void kernel_launch(void* const* d_in, const int* in_sizes, int n_in,
                              void* d_out, int out_size, void* d_ws, size_t ws_size,
                              hipStream_t stream) {
  const float* x  = (const float*)d_in[0];
  const float* W1 = (const float*)d_in[1];
  const float* b1 = (const float*)d_in[2];
  const float* W3 = (const float*)d_in[3];
  const float* b3 = (const float*)d_in[4];
  const float* W2 = (const float*)d_in[5];
  // d_in[6] = b2: cancels in softmax; d_in[7] = bag_lengths: shapes only
  float* out = (float*)d_out;

  char* ws = (char*)d_ws;                         // ~4.73 MB used
  short* wc    = (short*)(ws + 0);                // 512 KB concat bf16 weights
  short* part  = (short*)(ws + 524288);           // 4 MB  [1024][4][512] bf16 partials
  float* psumP = (float*)(ws + 524288 + 4194304); // 16 KB [1024][4]

  hipLaunchKernelGGL(k_prep_w,   dim3(128),  dim3(256), 0, stream, W1, W3, wc);
  hipLaunchKernelGGL(k_fused,    dim3(1024), dim3(512), 0, stream, x, wc, b1, b3, W2, part, psumP);
  hipLaunchKernelGGL(k_finalize, dim3(256),  dim3(256), 0, stream, part, psumP, out);
}